// Round 10
// baseline (323.887 us; speedup 1.0000x reference)
//
#include <hip/hip_runtime.h>
#include <cmath>

#define IN_F 128
#define NEG_SLOPE 0.2f
#define SEG 64              // per-node fast-path max in-degree
#define BSHIFT 7            // 128 nodes per bucket
#define NBMAX 1024          // supports N <= 131072
#define CHUNK 2048          // bscatter chunk; 2048 beats 8192 (R6/R7 A/B: occupancy)
#define SLOT 4096           // over-allocated edge slots per bucket
#define LDSTRIDE 136        // bf16 elements; LDS row stride (2-way bank alias = free)

typedef short bfrag8 __attribute__((ext_vector_type(8)));
typedef float facc4 __attribute__((ext_vector_type(4)));
typedef float v2f __attribute__((ext_vector_type(2)));

__device__ __forceinline__ int ldidx(const int* ei, int pos, int is64) {
  return is64 ? ei[2 * pos] : ei[pos];
}
__device__ __forceinline__ unsigned short f2b(float f) {
  unsigned u = __float_as_uint(f);
  u += 0x7fffu + ((u >> 16) & 1u);   // RNE (inputs never NaN)
  return (unsigned short)(u >> 16);
}
__device__ __forceinline__ float b2f_lo(unsigned u) { return __uint_as_float(u << 16); }
__device__ __forceinline__ float b2f_hi(unsigned u) { return __uint_as_float(u & 0xffff0000u); }
__device__ __forceinline__ v2f b2f2(unsigned u) {
  v2f r; r.x = b2f_lo(u); r.y = b2f_hi(u); return r;
}
__device__ __forceinline__ void wave_lds_fence() {
  asm volatile("s_waitcnt lgkmcnt(0)" ::: "memory");
}
__device__ __forceinline__ float leaky(float l) { return fmaxf(l, NEG_SLOPE * l); }
__device__ __forceinline__ float elu(float o) { return o > 0.f ? o : __expf(o) - 1.f; }

// ---------- merged prologue: detect dtype | init bucket cursors | W1/W2 -> bf16 transposed ----------
__global__ __launch_bounds__(256) void prologue_kernel(
    const int* __restrict__ ei, int E, int* __restrict__ flag,
    int* __restrict__ bcur, int NB,
    const float* __restrict__ W1, const float* __restrict__ W2,
    unsigned short* __restrict__ Wt1g, unsigned short* __restrict__ Wt2g) {
  int b = blockIdx.x, tid = threadIdx.x;
  if (b == 0) {
    __shared__ int red[256];
    int acc = 0;
    int limit = E < 4096 ? E : 4096;
    for (int j = tid; j < limit; j += 256) acc |= ei[2 * j + 1];
    red[tid] = acc;
    __syncthreads();
    for (int s = 128; s > 0; s >>= 1) {
      if (tid < s) red[tid] |= red[tid + s];
      __syncthreads();
    }
    if (tid == 0) *flag = (red[0] == 0) ? 1 : 0;
  } else if (b == 1) {
    for (int i = tid; i < NB; i += 256) bcur[i] = i * SLOT;
  } else if (b < 8) {
    for (int i = (b - 2) * 256 + tid; i < 128 * 128; i += 6 * 256) {
      int k = i >> 7, c = i & 127;
      Wt1g[c * 128 + k] = f2b(W1[i]);
    }
  } else {
    for (int i = (b - 8) * 256 + tid; i < 128 * 64; i += 6 * 256) {
      int k = i >> 6, c = i & 63;
      Wt2g[c * 128 + k] = f2b(W2[i]);
    }
  }
}

// ---------- FUSED: bucket scatter (blocks < nchunk) | GEMM1 MFMA (remaining blocks) ----------
__global__ __launch_bounds__(256) void scatter_gemm1_kernel(
    const int* __restrict__ ei, int E, int Etot, const int* __restrict__ flag,
    int NB, int nchunk, int* __restrict__ bcur, unsigned* __restrict__ ebuf,
    const float* __restrict__ x, const unsigned short* __restrict__ Wt1g,
    const float* __restrict__ asr, const float* __restrict__ ads,
    unsigned short* __restrict__ h1b, float* __restrict__ es, float* __restrict__ ed,
    int N) {
  __shared__ __align__(16) char smem[52224];
  int tid = threadIdx.x;

  if ((int)blockIdx.x < nchunk) {
    // ---- scatter role ----
    int* hcnt = (int*)smem;
    int* hcur = (int*)(smem + 4096);
    int base = blockIdx.x * CHUNK;
    int cnt = Etot - base; if (cnt > CHUNK) cnt = CHUNK;
    int is64 = *flag;
    for (int i = tid; i < NB; i += 256) hcnt[i] = 0;
    __syncthreads();
    for (int i = tid; i < cnt; i += 256) {
      int e = base + i;
      int d = (e < E) ? ldidx(ei, E + e, is64) : (e - E);
      atomicAdd(&hcnt[d >> BSHIFT], 1);
    }
    __syncthreads();
    for (int i = tid; i < NB; i += 256) {
      int c = hcnt[i];
      hcur[i] = c ? atomicAdd(&bcur[i], c) : 0;
    }
    __syncthreads();
    for (int i = tid; i < cnt; i += 256) {
      int e = base + i;
      int s, d;
      if (e < E) { s = ldidx(ei, e, is64); d = ldidx(ei, E + e, is64); }
      else       { s = e - E; d = s; }
      int pos = atomicAdd(&hcur[d >> BSHIFT], 1);
      ebuf[pos] = ((unsigned)s << 7) | ((unsigned)d & 127u);
    }
    return;
  }

  // ---- gemm1 role ----
  short* Wt = (short*)smem;               // 128 * LDSTRIDE shorts
  short* As = (short*)(smem + 34816);     // 64 * LDSTRIDE shorts
  int row0 = (blockIdx.x - nchunk) * 64;
  int lane = tid & 63, wv = tid >> 6;
  int m2 = lane & 15, quad = lane >> 4;

  for (int i = tid; i < 128 * 16; i += 256) {
    int c = i >> 4, ch = i & 15;
    *(uint4*)&Wt[c * LDSTRIDE + ch * 8] = *(const uint4*)&Wt1g[c * 128 + ch * 8];
  }
  for (int idx = tid; idx < 64 * 16; idx += 256) {
    int r = idx >> 4, ch = idx & 15;
    int n = row0 + r;
    bfrag8 sv;
    if (n < N) {
      float4 v0 = *(const float4*)&x[(size_t)n * 128 + ch * 8];
      float4 v1 = *(const float4*)&x[(size_t)n * 128 + ch * 8 + 4];
      sv[0] = (short)f2b(v0.x); sv[1] = (short)f2b(v0.y);
      sv[2] = (short)f2b(v0.z); sv[3] = (short)f2b(v0.w);
      sv[4] = (short)f2b(v1.x); sv[5] = (short)f2b(v1.y);
      sv[6] = (short)f2b(v1.z); sv[7] = (short)f2b(v1.w);
    } else {
      sv = (bfrag8)0;
    }
    *(bfrag8*)&As[r * LDSTRIDE + ch * 8] = sv;
  }
  __syncthreads();

  facc4 acc[8] = {};
  const short* Abase = &As[(wv * 16 + m2) * LDSTRIDE];
  #pragma unroll
  for (int ks = 0; ks < 4; ++ks) {
    int k = ks * 32 + quad * 8;
    bfrag8 af = *(const bfrag8*)&Abase[k];
    #pragma unroll
    for (int t = 0; t < 8; ++t) {
      bfrag8 bf = *(const bfrag8*)&Wt[(t * 16 + m2) * LDSTRIDE + k];
      acc[t] = __builtin_amdgcn_mfma_f32_16x16x32_bf16(af, bf, acc[t], 0, 0, 0);
    }
  }

  float av[8], bv[8];
  #pragma unroll
  for (int t = 0; t < 8; ++t) {
    int ai = (t >> 1) * 32 + (t & 1) * 16 + m2;
    av[t] = asr[ai]; bv[t] = ads[ai];
  }
  #pragma unroll
  for (int r = 0; r < 4; ++r) {
    int n = row0 + wv * 16 + quad * 4 + r;
    bool valid = (n < N);
    if (valid) {
      #pragma unroll
      for (int t = 0; t < 8; ++t)
        h1b[(size_t)n * 128 + t * 16 + m2] = f2b(acc[t][r]);
    }
    #pragma unroll
    for (int h = 0; h < 4; ++h) {
      float ps = acc[2 * h][r] * av[2 * h] + acc[2 * h + 1][r] * av[2 * h + 1];
      float pd = acc[2 * h][r] * bv[2 * h] + acc[2 * h + 1][r] * bv[2 * h + 1];
      ps += __shfl_xor(ps, 1); ps += __shfl_xor(ps, 2); ps += __shfl_xor(ps, 4); ps += __shfl_xor(ps, 8);
      pd += __shfl_xor(pd, 1); pd += __shfl_xor(pd, 2); pd += __shfl_xor(pd, 4); pd += __shfl_xor(pd, 8);
      if (valid && m2 == 0) {
        es[(size_t)n * 4 + h] = ps;
        ed[(size_t)n * 4 + h] = pd;
      }
    }
  }
}

// ---------- per-bucket CSR finalize, fully LDS-staged ----------
__global__ __launch_bounds__(256) void bcsr_kernel(const int* __restrict__ bcur, const unsigned* __restrict__ ebuf,
                                                   int* __restrict__ rowptr, int* __restrict__ rowdeg,
                                                   int* __restrict__ csr, int N, int NB) {
  __shared__ unsigned se[SLOT];
  __shared__ int scsr[SLOT];
  __shared__ int cnt[128];
  __shared__ int cur[128];
  __shared__ int w0sum;
  int tid = threadIdx.x;
  int b = blockIdx.x;
  int lo = b * SLOT, hi = bcur[b];
  int fill = hi - lo;
  int node0 = b << BSHIFT;
  int nn = N - node0; if (nn > 128) nn = 128;
  if (tid < 128) cnt[tid] = 0;
  for (int i = tid; i < fill; i += 256) se[i] = ebuf[lo + i];
  __syncthreads();
  for (int i = tid; i < fill; i += 256) {
    atomicAdd(&cnt[se[i] & 127u], 1);
  }
  __syncthreads();
  int v = 0, incl = 0;
  if (tid < 128) {
    v = cnt[tid];
    incl = v;
    int lane = tid & 63;
    #pragma unroll
    for (int off = 1; off < 64; off <<= 1) { int t = __shfl_up(incl, off); if (lane >= off) incl += t; }
    if (tid == 63) w0sum = incl;
  }
  __syncthreads();
  if (tid < 128) {
    if (tid >= 64) incl += w0sum;
    int excl = incl - v;
    cur[tid] = excl;
    if (tid < nn) {
      rowptr[node0 + tid] = lo + excl;
      rowdeg[node0 + tid] = v;
    }
  }
  __syncthreads();
  for (int i = tid; i < fill; i += 256) {
    unsigned pr = se[i];
    int p = atomicAdd(&cur[pr & 127u], 1);
    scsr[p] = (int)(pr >> 7);
  }
  __syncthreads();
  for (int i = tid; i < fill; i += 256) csr[lo + i] = scsr[i];
}

// ---------- FUSED Aggregation layer 1 + GEMM 2 ----------
// Block = 16 nodes. Phases A-C produce the 16 hmid rows in an LDS bf16 tile
// (identical f2b rounding as the old hmidb global store -> bit-identical
// numerics); then one syncthreads and each wave runs the 16x16xK=128 MFMA
// for its 16-col slice of W2, writing h2b + es2/ed2 directly. Removes the
// 51 MB hmidb round-trip and the separate gemm2 dispatch.
__global__ __launch_bounds__(256) void agg1_gemm2_kernel(
    const int* __restrict__ rowptr, const int* __restrict__ rowdeg, const int* __restrict__ csr,
    const float* __restrict__ es, const float* __restrict__ ed,
    const unsigned short* __restrict__ h1b, const float* __restrict__ bias1,
    const unsigned short* __restrict__ Wt2g, const float* __restrict__ asr2, const float* __restrict__ ads2,
    unsigned short* __restrict__ h2b, float* __restrict__ es2, float* __restrict__ ed2,
    int N) {
  __shared__ float lds_a[4][4][4][SEG + 4];
  __shared__ int   lds_s[4][4][SEG + 4];
  __shared__ short hm[16 * LDSTRIDE];       // 16 hmid rows, bf16, stride-136
  __shared__ float esp[16], edp[16];
  int tid = threadIdx.x;
  int wv = tid >> 6, lane = tid & 63;
  int sub = lane >> 4, sj = lane & 15;
  int bbase = blockIdx.x * 16;
  int nbase = bbase + wv * 4;
  int n = nbase + sub;
  bool nvalid = (n < N);
  int start = 0, len = 0;
  if (nvalid) { start = rowptr[n]; len = rowdeg[n]; }
  int lenc = (len <= SEG) ? len : 0;

  if (tid < 16) { esp[tid] = 0.f; edp[tid] = 0.f; }

  float4 edv = nvalid ? ((const float4*)ed)[n] : make_float4(0.f, 0.f, 0.f, 0.f);
  float l[4][4];
  float mx = -1e30f;
  #pragma unroll
  for (int it = 0; it < 4; ++it) {
    int j = sj + it * 16;
    if (j < lenc) {
      int s = csr[start + j];
      lds_s[wv][sub][j] = s;
      float4 ev = ((const float4*)es)[s];
      float l0 = leaky(ev.x + edv.x);
      float l1 = leaky(ev.y + edv.y);
      float l2 = leaky(ev.z + edv.z);
      float l3 = leaky(ev.w + edv.w);
      l[it][0] = l0; l[it][1] = l1; l[it][2] = l2; l[it][3] = l3;
      mx = fmaxf(mx, fmaxf(fmaxf(l0, l1), fmaxf(l2, l3)));
    } else {
      l[it][0] = -1e30f; l[it][1] = -1e30f; l[it][2] = -1e30f; l[it][3] = -1e30f;
    }
  }
  #pragma unroll
  for (int off = 1; off < 16; off <<= 1) mx = fmaxf(mx, __shfl_xor(mx, off));

  float s0 = 0.f, s1 = 0.f, s2 = 0.f, s3 = 0.f;
  #pragma unroll
  for (int it = 0; it < 4; ++it) {
    float p0 = __expf(l[it][0] - mx);
    float p1 = __expf(l[it][1] - mx);
    float p2 = __expf(l[it][2] - mx);
    float p3 = __expf(l[it][3] - mx);
    l[it][0] = p0; l[it][1] = p1; l[it][2] = p2; l[it][3] = p3;
    s0 += p0; s1 += p1; s2 += p2; s3 += p3;
  }
  #pragma unroll
  for (int off = 1; off < 16; off <<= 1) {
    s0 += __shfl_xor(s0, off); s1 += __shfl_xor(s1, off);
    s2 += __shfl_xor(s2, off); s3 += __shfl_xor(s3, off);
  }
  float i0 = __builtin_amdgcn_rcpf(s0 + 1e-16f);
  float i1 = __builtin_amdgcn_rcpf(s1 + 1e-16f);
  float i2 = __builtin_amdgcn_rcpf(s2 + 1e-16f);
  float i3 = __builtin_amdgcn_rcpf(s3 + 1e-16f);
  #pragma unroll
  for (int it = 0; it < 4; ++it) {
    int j = sj + it * 16;
    if (j < lenc) {
      lds_a[wv][sub][0][j] = l[it][0] * i0;
      lds_a[wv][sub][1][j] = l[it][1] * i1;
      lds_a[wv][sub][2][j] = l[it][2] * i2;
      lds_a[wv][sub][3][j] = l[it][3] * i3;
    }
  }
  if (sj == 0) {
    int lenp1 = (lenc + 3) & ~3;
    for (int t = lenc; t < lenp1; ++t) {
      lds_s[wv][sub][t] = 0;
      lds_a[wv][sub][0][t] = 0.f; lds_a[wv][sub][1][t] = 0.f;
      lds_a[wv][sub][2][t] = 0.f; lds_a[wv][sub][3][t] = 0.f;
    }
  }
  wave_lds_fence();

  int fl = lane & 15, eidx = lane >> 4, hd = fl >> 2;
  const uint4* hrow = (const uint4*)h1b;
  #pragma unroll 1
  for (int i = 0; i < 4; ++i) {
    int lenC = __shfl(lenc, i << 4);
    if (lenC == 0) continue;
    const int* sP = &lds_s[wv][i][0];
    const float* aP = &lds_a[wv][i][hd][0];
    int lenp = (lenC + 3) & ~3;
    v2f C0 = {0.f, 0.f}, C1 = {0.f, 0.f}, C2 = {0.f, 0.f}, C3 = {0.f, 0.f};
    v2f D0 = {0.f, 0.f}, D1 = {0.f, 0.f}, D2 = {0.f, 0.f}, D3 = {0.f, 0.f};
    int g = 0;
    for (; g + 8 <= lenp; g += 8) {
      int sA = sP[g + eidx], sB = sP[g + 4 + eidx];
      float wA = aP[g + eidx];
      float wB = aP[g + 4 + eidx];
      uint4 uA = hrow[(size_t)sA * 16 + fl];
      uint4 uB = hrow[(size_t)sB * 16 + fl];
      v2f wA2 = {wA, wA}, wB2 = {wB, wB};
      C0 = __builtin_elementwise_fma(b2f2(uA.x), wA2, C0);
      C1 = __builtin_elementwise_fma(b2f2(uA.y), wA2, C1);
      C2 = __builtin_elementwise_fma(b2f2(uA.z), wA2, C2);
      C3 = __builtin_elementwise_fma(b2f2(uA.w), wA2, C3);
      D0 = __builtin_elementwise_fma(b2f2(uB.x), wB2, D0);
      D1 = __builtin_elementwise_fma(b2f2(uB.y), wB2, D1);
      D2 = __builtin_elementwise_fma(b2f2(uB.z), wB2, D2);
      D3 = __builtin_elementwise_fma(b2f2(uB.w), wB2, D3);
    }
    if (g < lenp) {
      int sA = sP[g + eidx];
      float wA = aP[g + eidx];
      uint4 uA = hrow[(size_t)sA * 16 + fl];
      v2f wA2 = {wA, wA};
      C0 = __builtin_elementwise_fma(b2f2(uA.x), wA2, C0);
      C1 = __builtin_elementwise_fma(b2f2(uA.y), wA2, C1);
      C2 = __builtin_elementwise_fma(b2f2(uA.z), wA2, C2);
      C3 = __builtin_elementwise_fma(b2f2(uA.w), wA2, C3);
    }
    C0 += D0; C1 += D1; C2 += D2; C3 += D3;
    float c0 = C0.x, c1 = C0.y, c2 = C1.x, c3 = C1.y;
    float c4 = C2.x, c5 = C2.y, c6 = C3.x, c7 = C3.y;
    c0 += __shfl_xor(c0, 16); c1 += __shfl_xor(c1, 16); c2 += __shfl_xor(c2, 16); c3 += __shfl_xor(c3, 16);
    c4 += __shfl_xor(c4, 16); c5 += __shfl_xor(c5, 16); c6 += __shfl_xor(c6, 16); c7 += __shfl_xor(c7, 16);
    c0 += __shfl_xor(c0, 32); c1 += __shfl_xor(c1, 32); c2 += __shfl_xor(c2, 32); c3 += __shfl_xor(c3, 32);
    c4 += __shfl_xor(c4, 32); c5 += __shfl_xor(c5, 32); c6 += __shfl_xor(c6, 32); c7 += __shfl_xor(c7, 32);
    if (eidx == 0) {
      float4 ba = *(const float4*)&bias1[fl * 8];
      float4 bb = *(const float4*)&bias1[fl * 8 + 4];
      float o0 = elu(c0 + ba.x), o1 = elu(c1 + ba.y), o2 = elu(c2 + ba.z), o3 = elu(c3 + ba.w);
      float o4 = elu(c4 + bb.x), o5 = elu(c5 + bb.y), o6 = elu(c6 + bb.z), o7 = elu(c7 + bb.w);
      uint4 pk;
      pk.x = (unsigned)f2b(o0) | ((unsigned)f2b(o1) << 16);
      pk.y = (unsigned)f2b(o2) | ((unsigned)f2b(o3) << 16);
      pk.z = (unsigned)f2b(o4) | ((unsigned)f2b(o5) << 16);
      pk.w = (unsigned)f2b(o6) | ((unsigned)f2b(o7) << 16);
      int row = wv * 4 + i;
      *(uint4*)&hm[row * LDSTRIDE + fl * 8] = pk;
    }
  }

  // fallback: whole-wave per node for len > SEG
  #pragma unroll 1
  for (int i = 0; i < 4; ++i) {
    int lenF = __shfl(len, i << 4);
    if (lenF <= SEG) continue;
    int stF = __shfl(start, i << 4);
    int nI = nbase + i;
    float4 ed4 = ((const float4*)ed)[nI];
    int f = lane * 2, hh = lane >> 4;
    const unsigned* h32 = (const unsigned*)h1b;
    float m0 = -1e30f, m1 = -1e30f, m2v = -1e30f, m3 = -1e30f;
    for (int j = stF + lane; j < stF + lenF; j += 64) {
      int s = csr[j];
      float4 ev = ((const float4*)es)[s];
      m0 = fmaxf(m0, leaky(ev.x + ed4.x)); m1 = fmaxf(m1, leaky(ev.y + ed4.y));
      m2v = fmaxf(m2v, leaky(ev.z + ed4.z)); m3 = fmaxf(m3, leaky(ev.w + ed4.w));
    }
    #pragma unroll
    for (int off = 32; off; off >>= 1) {
      m0 = fmaxf(m0, __shfl_xor(m0, off)); m1 = fmaxf(m1, __shfl_xor(m1, off));
      m2v = fmaxf(m2v, __shfl_xor(m2v, off)); m3 = fmaxf(m3, __shfl_xor(m3, off));
    }
    float t0 = 0.f, t1 = 0.f, t2 = 0.f, t3 = 0.f;
    for (int j = stF + lane; j < stF + lenF; j += 64) {
      int s = csr[j];
      float4 ev = ((const float4*)es)[s];
      t0 += __expf(leaky(ev.x + ed4.x) - m0); t1 += __expf(leaky(ev.y + ed4.y) - m1);
      t2 += __expf(leaky(ev.z + ed4.z) - m2v); t3 += __expf(leaky(ev.w + ed4.w) - m3);
    }
    #pragma unroll
    for (int off = 32; off; off >>= 1) {
      t0 += __shfl_xor(t0, off); t1 += __shfl_xor(t1, off);
      t2 += __shfl_xor(t2, off); t3 += __shfl_xor(t3, off);
    }
    float j0 = 1.f / (t0 + 1e-16f), j1 = 1.f / (t1 + 1e-16f);
    float j2 = 1.f / (t2 + 1e-16f), j3 = 1.f / (t3 + 1e-16f);
    float edh = (hh & 2) ? ((hh & 1) ? ed4.w : ed4.z) : ((hh & 1) ? ed4.y : ed4.x);
    float mh  = (hh & 2) ? ((hh & 1) ? m3 : m2v) : ((hh & 1) ? m1 : m0);
    float ih  = (hh & 2) ? ((hh & 1) ? j3 : j2) : ((hh & 1) ? j1 : j0);
    float ax = 0.f, ay = 0.f;
    for (int j = stF; j < stF + lenF; ++j) {
      int s = csr[j];
      float lv = leaky(es[(size_t)s * 4 + hh] + edh);
      float a = __expf(lv - mh) * ih;
      unsigned u = h32[(size_t)s * 64 + lane];
      ax = fmaf(b2f_lo(u), a, ax);
      ay = fmaf(b2f_hi(u), a, ay);
    }
    float o0 = elu(ax + bias1[f]), o1 = elu(ay + bias1[f + 1]);
    unsigned packed = (unsigned)f2b(o0) | ((unsigned)f2b(o1) << 16);
    int row = wv * 4 + i;
    *(unsigned*)&hm[row * LDSTRIDE + lane * 2] = packed;
  }

  __syncthreads();   // publish hm tile + esp/edp zeros

  // ---- gemm2 phase: wave wv -> output cols [wv*16, wv*16+16) for all 16 rows ----
  facc4 acc2 = {};
  #pragma unroll
  for (int ks = 0; ks < 4; ++ks) {
    int k = ks * 32 + sub * 8;
    bfrag8 af = *(const bfrag8*)&hm[sj * LDSTRIDE + k];
    bfrag8 bf = *(const bfrag8*)&Wt2g[(size_t)(wv * 16 + sj) * 128 + k];
    acc2 = __builtin_amdgcn_mfma_f32_16x16x32_bf16(af, bf, acc2, 0, 0, 0);
  }
  float a2 = asr2[wv * 16 + sj], b2v = ads2[wv * 16 + sj];
  #pragma unroll
  for (int r = 0; r < 4; ++r) {
    int row = sub * 4 + r;
    int nO = bbase + row;
    if (nO < N) h2b[(size_t)nO * 64 + wv * 16 + sj] = f2b(acc2[r]);
    float ps = acc2[r] * a2;
    float pd = acc2[r] * b2v;
    ps += __shfl_xor(ps, 1); ps += __shfl_xor(ps, 2); ps += __shfl_xor(ps, 4); ps += __shfl_xor(ps, 8);
    pd += __shfl_xor(pd, 1); pd += __shfl_xor(pd, 2); pd += __shfl_xor(pd, 4); pd += __shfl_xor(pd, 8);
    if (sj == 0) {
      atomicAdd(&esp[row], ps);
      atomicAdd(&edp[row], pd);
    }
  }
  __syncthreads();
  if (tid < 16) {
    int nO = bbase + tid;
    if (nO < N) { es2[nO] = esp[tid]; ed2[nO] = edp[tid]; }
  }
}

// ---------- Aggregation layer 2 ----------
__global__ __launch_bounds__(256) void agg2_kernel(
    const int* __restrict__ rowptr, const int* __restrict__ rowdeg, const int* __restrict__ csr,
    const float* __restrict__ es, const float* __restrict__ ed,
    const unsigned short* __restrict__ h2b, const float* __restrict__ bias2,
    float* __restrict__ out, int N) {
  __shared__ float lds_a[4][4][SEG + 8];
  __shared__ int   lds_s[4][4][SEG + 8];
  int tid = threadIdx.x;
  int wv = tid >> 6, lane = tid & 63;
  int sub = lane >> 4, sj = lane & 15;
  int nbase = blockIdx.x * 16 + wv * 4;
  int n = nbase + sub;
  bool nvalid = (n < N);
  int start = 0, len = 0;
  if (nvalid) { start = rowptr[n]; len = rowdeg[n]; }
  int lenc = (len <= SEG) ? len : 0;

  float edv = nvalid ? ed[n] : 0.f;
  float l[4];
  float mx = -1e30f;
  #pragma unroll
  for (int it = 0; it < 4; ++it) {
    int j = sj + it * 16;
    if (j < lenc) {
      int s = csr[start + j];
      lds_s[wv][sub][j] = s;
      float lv = leaky(es[s] + edv);
      l[it] = lv;
      mx = fmaxf(mx, lv);
    } else {
      l[it] = -1e30f;
    }
  }
  #pragma unroll
  for (int off = 1; off < 16; off <<= 1) mx = fmaxf(mx, __shfl_xor(mx, off));
  float sm = 0.f;
  #pragma unroll
  for (int it = 0; it < 4; ++it) {
    float p = __expf(l[it] - mx);
    l[it] = p;
    sm += p;
  }
  #pragma unroll
  for (int off = 1; off < 16; off <<= 1) sm += __shfl_xor(sm, off);
  float inv = __builtin_amdgcn_rcpf(sm + 1e-16f);
  #pragma unroll
  for (int it = 0; it < 4; ++it) {
    int j = sj + it * 16;
    if (j < lenc) lds_a[wv][sub][j] = l[it] * inv;
  }
  if (sj == 0) {
    int lenp1 = (lenc + 7) & ~7;
    for (int t = lenc; t < lenp1; ++t) {
      lds_s[wv][sub][t] = 0;
      lds_a[wv][sub][t] = 0.f;
    }
  }
  wave_lds_fence();

  int fl = lane & 7, eidx = lane >> 3;
  const uint4* hrow = (const uint4*)h2b;
  #pragma unroll 1
  for (int i = 0; i < 4; ++i) {
    int lenC = __shfl(lenc, i << 4);
    if (lenC == 0) continue;
    int nI = nbase + i;
    const float* aP = &lds_a[wv][i][0];
    const int*   sP = &lds_s[wv][i][0];
    int lenp = (lenC + 7) & ~7;
    v2f C0 = {0.f, 0.f}, C1 = {0.f, 0.f}, C2 = {0.f, 0.f}, C3 = {0.f, 0.f};
    v2f D0 = {0.f, 0.f}, D1 = {0.f, 0.f}, D2 = {0.f, 0.f}, D3 = {0.f, 0.f};
    int g = 0;
    for (; g + 16 <= lenp; g += 16) {
      int sA = sP[g + eidx],   sB = sP[g + 8 + eidx];
      float wA = aP[g + eidx], wB = aP[g + 8 + eidx];
      uint4 uA = hrow[(size_t)sA * 8 + fl];
      uint4 uB = hrow[(size_t)sB * 8 + fl];
      v2f wA2 = {wA, wA}, wB2 = {wB, wB};
      C0 = __builtin_elementwise_fma(b2f2(uA.x), wA2, C0);
      C1 = __builtin_elementwise_fma(b2f2(uA.y), wA2, C1);
      C2 = __builtin_elementwise_fma(b2f2(uA.z), wA2, C2);
      C3 = __builtin_elementwise_fma(b2f2(uA.w), wA2, C3);
      D0 = __builtin_elementwise_fma(b2f2(uB.x), wB2, D0);
      D1 = __builtin_elementwise_fma(b2f2(uB.y), wB2, D1);
      D2 = __builtin_elementwise_fma(b2f2(uB.z), wB2, D2);
      D3 = __builtin_elementwise_fma(b2f2(uB.w), wB2, D3);
    }
    if (g < lenp) {
      int sA = sP[g + eidx];
      float wA = aP[g + eidx];
      uint4 uA = hrow[(size_t)sA * 8 + fl];
      v2f wA2 = {wA, wA};
      C0 = __builtin_elementwise_fma(b2f2(uA.x), wA2, C0);
      C1 = __builtin_elementwise_fma(b2f2(uA.y), wA2, C1);
      C2 = __builtin_elementwise_fma(b2f2(uA.z), wA2, C2);
      C3 = __builtin_elementwise_fma(b2f2(uA.w), wA2, C3);
    }
    C0 += D0; C1 += D1; C2 += D2; C3 += D3;
    float c0 = C0.x, c1 = C0.y, c2 = C1.x, c3 = C1.y;
    float c4 = C2.x, c5 = C2.y, c6 = C3.x, c7 = C3.y;
    c0 += __shfl_xor(c0, 8);  c1 += __shfl_xor(c1, 8);  c2 += __shfl_xor(c2, 8);  c3 += __shfl_xor(c3, 8);
    c4 += __shfl_xor(c4, 8);  c5 += __shfl_xor(c5, 8);  c6 += __shfl_xor(c6, 8);  c7 += __shfl_xor(c7, 8);
    c0 += __shfl_xor(c0, 16); c1 += __shfl_xor(c1, 16); c2 += __shfl_xor(c2, 16); c3 += __shfl_xor(c3, 16);
    c4 += __shfl_xor(c4, 16); c5 += __shfl_xor(c5, 16); c6 += __shfl_xor(c6, 16); c7 += __shfl_xor(c7, 16);
    c0 += __shfl_xor(c0, 32); c1 += __shfl_xor(c1, 32); c2 += __shfl_xor(c2, 32); c3 += __shfl_xor(c3, 32);
    c4 += __shfl_xor(c4, 32); c5 += __shfl_xor(c5, 32); c6 += __shfl_xor(c6, 32); c7 += __shfl_xor(c7, 32);
    if (eidx == 0) {
      float4 ba = *(const float4*)&bias2[fl * 8];
      float4 bb = *(const float4*)&bias2[fl * 8 + 4];
      ((float4*)out)[(size_t)nI * 16 + fl * 2]     = make_float4(c0 + ba.x, c1 + ba.y, c2 + ba.z, c3 + ba.w);
      ((float4*)out)[(size_t)nI * 16 + fl * 2 + 1] = make_float4(c4 + bb.x, c5 + bb.y, c6 + bb.z, c7 + bb.w);
    }
  }

  // fallback for len > SEG
  #pragma unroll 1
  for (int i = 0; i < 4; ++i) {
    int lenF = __shfl(len, i << 4);
    if (lenF <= SEG) continue;
    int stF = __shfl(start, i << 4);
    int nI = nbase + i;
    float edF = ed[nI];
    float m = -1e30f;
    for (int j = stF + lane; j < stF + lenF; j += 64) {
      m = fmaxf(m, leaky(es[csr[j]] + edF));
    }
    #pragma unroll
    for (int off = 32; off; off >>= 1) m = fmaxf(m, __shfl_xor(m, off));
    float t = 0.f;
    for (int j = stF + lane; j < stF + lenF; j += 64) {
      t += __expf(leaky(es[csr[j]] + edF) - m);
    }
    #pragma unroll
    for (int off = 32; off; off >>= 1) t += __shfl_xor(t, off);
    float iv = 1.f / (t + 1e-16f);
    float acc = 0.f;
    for (int j = stF; j < stF + lenF; ++j) {
      int s = csr[j];
      float a = __expf(leaky(es[s] + edF) - m) * iv;
      float v = __uint_as_float(((unsigned)h2b[(size_t)s * 64 + lane]) << 16);
      acc = fmaf(v, a, acc);
    }
    out[(size_t)nI * 64 + lane] = acc + bias2[lane];
  }
}

extern "C" void kernel_launch(void* const* d_in, const int* in_sizes, int n_in,
                              void* d_out, int out_size, void* d_ws, size_t ws_size,
                              hipStream_t stream) {
  const float* x   = (const float*)d_in[0];
  const int*   ei  = (const int*)d_in[1];
  const float* W1  = (const float*)d_in[2];
  const float* as1 = (const float*)d_in[3];
  const float* ad1 = (const float*)d_in[4];
  const float* b1  = (const float*)d_in[5];
  const float* W2  = (const float*)d_in[6];
  const float* as2 = (const float*)d_in[7];
  const float* ad2 = (const float*)d_in[8];
  const float* b2  = (const float*)d_in[9];
  float* out = (float*)d_out;

  int N = in_sizes[0] / IN_F;
  int E = in_sizes[1] / 2;
  int Etot = E + N;
  int NB = (N + 127) >> BSHIFT;

  char* p = (char*)d_ws;
  auto carve = [&](size_t bytes) -> char* {
    char* r = p;
    p += (bytes + 255) & ~(size_t)255;
    return r;
  };
  int* flag     = (int*)carve(4);
  int* bcur     = (int*)carve((size_t)NBMAX * 4);
  unsigned short* Wt1g = (unsigned short*)carve(128 * 128 * 2);
  unsigned short* Wt2g = (unsigned short*)carve(64 * 128 * 2);
  unsigned* ebuf = (unsigned*)carve((size_t)NB * SLOT * 4);
  int* rowptr   = (int*)carve((size_t)(N + 1) * 4);
  int* rowdeg   = (int*)carve((size_t)(N + 1) * 4);
  int* csr      = (int*)carve((size_t)NB * SLOT * 4);
  float* es1    = (float*)carve((size_t)N * 4 * 4);
  float* ed1    = (float*)carve((size_t)N * 4 * 4);
  float* es2    = (float*)carve((size_t)N * 4);
  float* ed2    = (float*)carve((size_t)N * 4);
  unsigned short* h1b   = (unsigned short*)carve((size_t)N * 128 * 2);
  unsigned short* h2b   = (unsigned short*)carve((size_t)N * 64 * 2);

  int nchunk = (Etot + CHUNK - 1) / CHUNK;
  int gblocks = (N + 63) / 64;
  prologue_kernel<<<14, 256, 0, stream>>>(ei, E, flag, bcur, NB, W1, W2, Wt1g, Wt2g);
  scatter_gemm1_kernel<<<nchunk + gblocks, 256, 0, stream>>>(
      ei, E, Etot, flag, NB, nchunk, bcur, ebuf,
      x, Wt1g, as1, ad1, h1b, es1, ed1, N);
  bcsr_kernel<<<NB, 256, 0, stream>>>(bcur, ebuf, rowptr, rowdeg, csr, N, NB);
  agg1_gemm2_kernel<<<(N + 15) / 16, 256, 0, stream>>>(
      rowptr, rowdeg, csr, es1, ed1, h1b, b1,
      Wt2g, as2, ad2, h2b, es2, ed2, N);
  agg2_kernel<<<(N + 15) / 16, 256, 0, stream>>>(rowptr, rowdeg, csr, es2, ed2, h2b, b2, out, N);
}

// Round 11
// 321.270 us; speedup vs baseline: 1.0081x; 1.0081x over previous
//
#include <hip/hip_runtime.h>
#include <cmath>

#define IN_F 128
#define NEG_SLOPE 0.2f
#define SEG 64              // per-node fast-path max in-degree
#define BSHIFT 7            // 128 nodes per bucket
#define NBMAX 1024          // supports N <= 131072
#define CHUNK 2048          // bscatter chunk; 2048 beats 8192 (R6/R7 A/B: occupancy)
#define SLOT 4096           // over-allocated edge slots per bucket
#define LDSTRIDE 136        // bf16 elements; LDS row stride (2-way bank alias = free)

typedef short bfrag8 __attribute__((ext_vector_type(8)));
typedef float facc4 __attribute__((ext_vector_type(4)));
typedef float v2f __attribute__((ext_vector_type(2)));

__device__ __forceinline__ int ldidx(const int* ei, int pos, int is64) {
  return is64 ? ei[2 * pos] : ei[pos];
}
__device__ __forceinline__ unsigned short f2b(float f) {
  unsigned u = __float_as_uint(f);
  u += 0x7fffu + ((u >> 16) & 1u);   // RNE (inputs never NaN)
  return (unsigned short)(u >> 16);
}
__device__ __forceinline__ float b2f_lo(unsigned u) { return __uint_as_float(u << 16); }
__device__ __forceinline__ float b2f_hi(unsigned u) { return __uint_as_float(u & 0xffff0000u); }
__device__ __forceinline__ v2f b2f2(unsigned u) {
  v2f r; r.x = b2f_lo(u); r.y = b2f_hi(u); return r;
}
__device__ __forceinline__ void wave_lds_fence() {
  asm volatile("s_waitcnt lgkmcnt(0)" ::: "memory");
}
__device__ __forceinline__ float leaky(float l) { return fmaxf(l, NEG_SLOPE * l); }
__device__ __forceinline__ float elu(float o) { return o > 0.f ? o : __expf(o) - 1.f; }

// ---------- merged prologue: detect dtype | init bucket cursors | W1/W2 -> bf16 transposed ----------
__global__ __launch_bounds__(256) void prologue_kernel(
    const int* __restrict__ ei, int E, int* __restrict__ flag,
    int* __restrict__ bcur, int NB,
    const float* __restrict__ W1, const float* __restrict__ W2,
    unsigned short* __restrict__ Wt1g, unsigned short* __restrict__ Wt2g) {
  int b = blockIdx.x, tid = threadIdx.x;
  if (b == 0) {
    __shared__ int red[256];
    int acc = 0;
    int limit = E < 4096 ? E : 4096;
    for (int j = tid; j < limit; j += 256) acc |= ei[2 * j + 1];
    red[tid] = acc;
    __syncthreads();
    for (int s = 128; s > 0; s >>= 1) {
      if (tid < s) red[tid] |= red[tid + s];
      __syncthreads();
    }
    if (tid == 0) *flag = (red[0] == 0) ? 1 : 0;
  } else if (b == 1) {
    for (int i = tid; i < NB; i += 256) bcur[i] = i * SLOT;
  } else if (b < 8) {
    for (int i = (b - 2) * 256 + tid; i < 128 * 128; i += 6 * 256) {
      int k = i >> 7, c = i & 127;
      Wt1g[c * 128 + k] = f2b(W1[i]);
    }
  } else {
    for (int i = (b - 8) * 256 + tid; i < 128 * 64; i += 6 * 256) {
      int k = i >> 6, c = i & 63;
      Wt2g[c * 128 + k] = f2b(W2[i]);
    }
  }
}

// ---------- bucket scatter (standalone; 8 KB LDS -> high occupancy) ----------
__global__ __launch_bounds__(256) void bscatter_kernel(const int* __restrict__ ei, int E, int Etot,
                                                       const int* __restrict__ flag, int NB,
                                                       int* __restrict__ bcur, unsigned* __restrict__ ebuf) {
  __shared__ int hcnt[NBMAX];
  __shared__ int hcur[NBMAX];
  int tid = threadIdx.x;
  int base = blockIdx.x * CHUNK;
  int cnt = Etot - base; if (cnt > CHUNK) cnt = CHUNK;
  int is64 = *flag;
  for (int i = tid; i < NB; i += 256) hcnt[i] = 0;
  __syncthreads();
  for (int i = tid; i < cnt; i += 256) {
    int e = base + i;
    int d = (e < E) ? ldidx(ei, E + e, is64) : (e - E);
    atomicAdd(&hcnt[d >> BSHIFT], 1);
  }
  __syncthreads();
  for (int i = tid; i < NB; i += 256) {
    int c = hcnt[i];
    hcur[i] = c ? atomicAdd(&bcur[i], c) : 0;
  }
  __syncthreads();
  for (int i = tid; i < cnt; i += 256) {
    int e = base + i;
    int s, d;
    if (e < E) { s = ldidx(ei, e, is64); d = ldidx(ei, E + e, is64); }
    else       { s = e - E; d = s; }
    int pos = atomicAdd(&hcur[d >> BSHIFT], 1);
    ebuf[pos] = ((unsigned)s << 7) | ((unsigned)d & 127u);
  }
}

// ---------- FUSED: per-bucket CSR finalize (blocks < NB) | GEMM1 MFMA (remaining) ----------
// Independent roles: bcsr reads ebuf/bcur (from scatter) -> writes rowptr/rowdeg/csr;
// gemm1 reads x/Wt1g -> writes h1b/es/ed. Different blocks -> true concurrency, and
// h1b + csr are both freshly written in L2 right before agg1 runs.
__global__ __launch_bounds__(256) void bcsr_gemm1_kernel(
    const int* __restrict__ bcur, const unsigned* __restrict__ ebuf,
    int* __restrict__ rowptr, int* __restrict__ rowdeg, int* __restrict__ csr,
    int NB,
    const float* __restrict__ x, const unsigned short* __restrict__ Wt1g,
    const float* __restrict__ asr, const float* __restrict__ ads,
    unsigned short* __restrict__ h1b, float* __restrict__ es, float* __restrict__ ed,
    int N) {
  __shared__ __align__(16) char smem[52224];
  int tid = threadIdx.x;

  if ((int)blockIdx.x < NB) {
    // ---- bcsr role (33.8 KB of the union) ----
    unsigned* se = (unsigned*)smem;              // SLOT * 4 = 16384
    int* scsr    = (int*)(smem + 16384);         // 16384
    int* cnt     = (int*)(smem + 32768);         // 512
    int* cur     = (int*)(smem + 33280);         // 512
    int* w0      = (int*)(smem + 33792);         // 4
    int b = blockIdx.x;
    int lo = b * SLOT, hi = bcur[b];
    int fill = hi - lo;
    int node0 = b << BSHIFT;
    int nn = N - node0; if (nn > 128) nn = 128;
    if (tid < 128) cnt[tid] = 0;
    for (int i = tid; i < fill; i += 256) se[i] = ebuf[lo + i];
    __syncthreads();
    for (int i = tid; i < fill; i += 256) {
      atomicAdd(&cnt[se[i] & 127u], 1);
    }
    __syncthreads();
    int v = 0, incl = 0;
    if (tid < 128) {
      v = cnt[tid];
      incl = v;
      int lane = tid & 63;
      #pragma unroll
      for (int off = 1; off < 64; off <<= 1) { int t = __shfl_up(incl, off); if (lane >= off) incl += t; }
      if (tid == 63) *w0 = incl;
    }
    __syncthreads();
    if (tid < 128) {
      if (tid >= 64) incl += *w0;
      int excl = incl - v;
      cur[tid] = excl;
      if (tid < nn) {
        rowptr[node0 + tid] = lo + excl;
        rowdeg[node0 + tid] = v;
      }
    }
    __syncthreads();
    for (int i = tid; i < fill; i += 256) {
      unsigned pr = se[i];
      int p = atomicAdd(&cur[pr & 127u], 1);
      scsr[p] = (int)(pr >> 7);
    }
    __syncthreads();
    for (int i = tid; i < fill; i += 256) csr[lo + i] = scsr[i];
    return;
  }

  // ---- gemm1 role ----
  short* Wt = (short*)smem;               // 128 * LDSTRIDE shorts = 34816 B
  short* As = (short*)(smem + 34816);     // 64 * LDSTRIDE shorts = 17408 B
  int row0 = (blockIdx.x - NB) * 64;
  int lane = tid & 63, wv = tid >> 6;
  int m2 = lane & 15, quad = lane >> 4;

  for (int i = tid; i < 128 * 16; i += 256) {
    int c = i >> 4, ch = i & 15;
    *(uint4*)&Wt[c * LDSTRIDE + ch * 8] = *(const uint4*)&Wt1g[c * 128 + ch * 8];
  }
  for (int idx = tid; idx < 64 * 16; idx += 256) {
    int r = idx >> 4, ch = idx & 15;
    int n = row0 + r;
    bfrag8 sv;
    if (n < N) {
      float4 v0 = *(const float4*)&x[(size_t)n * 128 + ch * 8];
      float4 v1 = *(const float4*)&x[(size_t)n * 128 + ch * 8 + 4];
      sv[0] = (short)f2b(v0.x); sv[1] = (short)f2b(v0.y);
      sv[2] = (short)f2b(v0.z); sv[3] = (short)f2b(v0.w);
      sv[4] = (short)f2b(v1.x); sv[5] = (short)f2b(v1.y);
      sv[6] = (short)f2b(v1.z); sv[7] = (short)f2b(v1.w);
    } else {
      sv = (bfrag8)0;
    }
    *(bfrag8*)&As[r * LDSTRIDE + ch * 8] = sv;
  }
  __syncthreads();

  facc4 acc[8] = {};
  const short* Abase = &As[(wv * 16 + m2) * LDSTRIDE];
  #pragma unroll
  for (int ks = 0; ks < 4; ++ks) {
    int k = ks * 32 + quad * 8;
    bfrag8 af = *(const bfrag8*)&Abase[k];
    #pragma unroll
    for (int t = 0; t < 8; ++t) {
      bfrag8 bf = *(const bfrag8*)&Wt[(t * 16 + m2) * LDSTRIDE + k];
      acc[t] = __builtin_amdgcn_mfma_f32_16x16x32_bf16(af, bf, acc[t], 0, 0, 0);
    }
  }

  float av[8], bv[8];
  #pragma unroll
  for (int t = 0; t < 8; ++t) {
    int ai = (t >> 1) * 32 + (t & 1) * 16 + m2;
    av[t] = asr[ai]; bv[t] = ads[ai];
  }
  #pragma unroll
  for (int r = 0; r < 4; ++r) {
    int n = row0 + wv * 16 + quad * 4 + r;
    bool valid = (n < N);
    if (valid) {
      #pragma unroll
      for (int t = 0; t < 8; ++t)
        h1b[(size_t)n * 128 + t * 16 + m2] = f2b(acc[t][r]);
    }
    #pragma unroll
    for (int h = 0; h < 4; ++h) {
      float ps = acc[2 * h][r] * av[2 * h] + acc[2 * h + 1][r] * av[2 * h + 1];
      float pd = acc[2 * h][r] * bv[2 * h] + acc[2 * h + 1][r] * bv[2 * h + 1];
      ps += __shfl_xor(ps, 1); ps += __shfl_xor(ps, 2); ps += __shfl_xor(ps, 4); ps += __shfl_xor(ps, 8);
      pd += __shfl_xor(pd, 1); pd += __shfl_xor(pd, 2); pd += __shfl_xor(pd, 4); pd += __shfl_xor(pd, 8);
      if (valid && m2 == 0) {
        es[(size_t)n * 4 + h] = ps;
        ed[(size_t)n * 4 + h] = pd;
      }
    }
  }
}

// ---------- Aggregation layer 1 (R9 version, untouched) ----------
__global__ __launch_bounds__(256) void agg1_kernel(
    const int* __restrict__ rowptr, const int* __restrict__ rowdeg, const int* __restrict__ csr,
    const float* __restrict__ es, const float* __restrict__ ed,
    const unsigned short* __restrict__ h1b, const float* __restrict__ bias1,
    unsigned short* __restrict__ hmidb, int N) {
  __shared__ float lds_a[4][4][4][SEG + 4];
  __shared__ int   lds_s[4][4][SEG + 4];
  int tid = threadIdx.x;
  int wv = tid >> 6, lane = tid & 63;
  int sub = lane >> 4, sj = lane & 15;
  int nbase = blockIdx.x * 16 + wv * 4;
  int n = nbase + sub;
  bool nvalid = (n < N);
  int start = 0, len = 0;
  if (nvalid) { start = rowptr[n]; len = rowdeg[n]; }
  int lenc = (len <= SEG) ? len : 0;

  float4 edv = nvalid ? ((const float4*)ed)[n] : make_float4(0.f, 0.f, 0.f, 0.f);
  float l[4][4];
  float mx = -1e30f;
  #pragma unroll
  for (int it = 0; it < 4; ++it) {
    int j = sj + it * 16;
    if (j < lenc) {
      int s = csr[start + j];
      lds_s[wv][sub][j] = s;
      float4 ev = ((const float4*)es)[s];
      float l0 = leaky(ev.x + edv.x);
      float l1 = leaky(ev.y + edv.y);
      float l2 = leaky(ev.z + edv.z);
      float l3 = leaky(ev.w + edv.w);
      l[it][0] = l0; l[it][1] = l1; l[it][2] = l2; l[it][3] = l3;
      mx = fmaxf(mx, fmaxf(fmaxf(l0, l1), fmaxf(l2, l3)));
    } else {
      l[it][0] = -1e30f; l[it][1] = -1e30f; l[it][2] = -1e30f; l[it][3] = -1e30f;
    }
  }
  #pragma unroll
  for (int off = 1; off < 16; off <<= 1) mx = fmaxf(mx, __shfl_xor(mx, off));

  float s0 = 0.f, s1 = 0.f, s2 = 0.f, s3 = 0.f;
  #pragma unroll
  for (int it = 0; it < 4; ++it) {
    float p0 = __expf(l[it][0] - mx);
    float p1 = __expf(l[it][1] - mx);
    float p2 = __expf(l[it][2] - mx);
    float p3 = __expf(l[it][3] - mx);
    l[it][0] = p0; l[it][1] = p1; l[it][2] = p2; l[it][3] = p3;
    s0 += p0; s1 += p1; s2 += p2; s3 += p3;
  }
  #pragma unroll
  for (int off = 1; off < 16; off <<= 1) {
    s0 += __shfl_xor(s0, off); s1 += __shfl_xor(s1, off);
    s2 += __shfl_xor(s2, off); s3 += __shfl_xor(s3, off);
  }
  float i0 = __builtin_amdgcn_rcpf(s0 + 1e-16f);
  float i1 = __builtin_amdgcn_rcpf(s1 + 1e-16f);
  float i2 = __builtin_amdgcn_rcpf(s2 + 1e-16f);
  float i3 = __builtin_amdgcn_rcpf(s3 + 1e-16f);
  #pragma unroll
  for (int it = 0; it < 4; ++it) {
    int j = sj + it * 16;
    if (j < lenc) {
      lds_a[wv][sub][0][j] = l[it][0] * i0;
      lds_a[wv][sub][1][j] = l[it][1] * i1;
      lds_a[wv][sub][2][j] = l[it][2] * i2;
      lds_a[wv][sub][3][j] = l[it][3] * i3;
    }
  }
  if (sj == 0) {
    int lenp1 = (lenc + 3) & ~3;
    for (int t = lenc; t < lenp1; ++t) {
      lds_s[wv][sub][t] = 0;
      lds_a[wv][sub][0][t] = 0.f; lds_a[wv][sub][1][t] = 0.f;
      lds_a[wv][sub][2][t] = 0.f; lds_a[wv][sub][3][t] = 0.f;
    }
  }
  wave_lds_fence();

  int fl = lane & 15, eidx = lane >> 4, hd = fl >> 2;
  const uint4* hrow = (const uint4*)h1b;
  #pragma unroll 1
  for (int i = 0; i < 4; ++i) {
    int lenC = __shfl(lenc, i << 4);
    if (lenC == 0) continue;
    int nI = nbase + i;
    const int* sP = &lds_s[wv][i][0];
    const float* aP = &lds_a[wv][i][hd][0];
    int lenp = (lenC + 3) & ~3;
    v2f C0 = {0.f, 0.f}, C1 = {0.f, 0.f}, C2 = {0.f, 0.f}, C3 = {0.f, 0.f};
    v2f D0 = {0.f, 0.f}, D1 = {0.f, 0.f}, D2 = {0.f, 0.f}, D3 = {0.f, 0.f};
    int g = 0;
    for (; g + 8 <= lenp; g += 8) {
      int sA = sP[g + eidx], sB = sP[g + 4 + eidx];
      float wA = aP[g + eidx];
      float wB = aP[g + 4 + eidx];
      uint4 uA = hrow[(size_t)sA * 16 + fl];
      uint4 uB = hrow[(size_t)sB * 16 + fl];
      v2f wA2 = {wA, wA}, wB2 = {wB, wB};
      C0 = __builtin_elementwise_fma(b2f2(uA.x), wA2, C0);
      C1 = __builtin_elementwise_fma(b2f2(uA.y), wA2, C1);
      C2 = __builtin_elementwise_fma(b2f2(uA.z), wA2, C2);
      C3 = __builtin_elementwise_fma(b2f2(uA.w), wA2, C3);
      D0 = __builtin_elementwise_fma(b2f2(uB.x), wB2, D0);
      D1 = __builtin_elementwise_fma(b2f2(uB.y), wB2, D1);
      D2 = __builtin_elementwise_fma(b2f2(uB.z), wB2, D2);
      D3 = __builtin_elementwise_fma(b2f2(uB.w), wB2, D3);
    }
    if (g < lenp) {
      int sA = sP[g + eidx];
      float wA = aP[g + eidx];
      uint4 uA = hrow[(size_t)sA * 16 + fl];
      v2f wA2 = {wA, wA};
      C0 = __builtin_elementwise_fma(b2f2(uA.x), wA2, C0);
      C1 = __builtin_elementwise_fma(b2f2(uA.y), wA2, C1);
      C2 = __builtin_elementwise_fma(b2f2(uA.z), wA2, C2);
      C3 = __builtin_elementwise_fma(b2f2(uA.w), wA2, C3);
    }
    C0 += D0; C1 += D1; C2 += D2; C3 += D3;
    float c0 = C0.x, c1 = C0.y, c2 = C1.x, c3 = C1.y;
    float c4 = C2.x, c5 = C2.y, c6 = C3.x, c7 = C3.y;
    c0 += __shfl_xor(c0, 16); c1 += __shfl_xor(c1, 16); c2 += __shfl_xor(c2, 16); c3 += __shfl_xor(c3, 16);
    c4 += __shfl_xor(c4, 16); c5 += __shfl_xor(c5, 16); c6 += __shfl_xor(c6, 16); c7 += __shfl_xor(c7, 16);
    c0 += __shfl_xor(c0, 32); c1 += __shfl_xor(c1, 32); c2 += __shfl_xor(c2, 32); c3 += __shfl_xor(c3, 32);
    c4 += __shfl_xor(c4, 32); c5 += __shfl_xor(c5, 32); c6 += __shfl_xor(c6, 32); c7 += __shfl_xor(c7, 32);
    if (eidx == 0) {
      float4 ba = *(const float4*)&bias1[fl * 8];
      float4 bb = *(const float4*)&bias1[fl * 8 + 4];
      float o0 = elu(c0 + ba.x), o1 = elu(c1 + ba.y), o2 = elu(c2 + ba.z), o3 = elu(c3 + ba.w);
      float o4 = elu(c4 + bb.x), o5 = elu(c5 + bb.y), o6 = elu(c6 + bb.z), o7 = elu(c7 + bb.w);
      uint4 pk;
      pk.x = (unsigned)f2b(o0) | ((unsigned)f2b(o1) << 16);
      pk.y = (unsigned)f2b(o2) | ((unsigned)f2b(o3) << 16);
      pk.z = (unsigned)f2b(o4) | ((unsigned)f2b(o5) << 16);
      pk.w = (unsigned)f2b(o6) | ((unsigned)f2b(o7) << 16);
      ((uint4*)hmidb)[(size_t)nI * 16 + fl] = pk;
    }
  }

  // fallback: whole-wave per node for len > SEG
  #pragma unroll 1
  for (int i = 0; i < 4; ++i) {
    int lenF = __shfl(len, i << 4);
    if (lenF <= SEG) continue;
    int stF = __shfl(start, i << 4);
    int nI = nbase + i;
    float4 ed4 = ((const float4*)ed)[nI];
    int f = lane * 2, hh = lane >> 4;
    const unsigned* h32 = (const unsigned*)h1b;
    float m0 = -1e30f, m1 = -1e30f, m2v = -1e30f, m3 = -1e30f;
    for (int j = stF + lane; j < stF + lenF; j += 64) {
      int s = csr[j];
      float4 ev = ((const float4*)es)[s];
      m0 = fmaxf(m0, leaky(ev.x + ed4.x)); m1 = fmaxf(m1, leaky(ev.y + ed4.y));
      m2v = fmaxf(m2v, leaky(ev.z + ed4.z)); m3 = fmaxf(m3, leaky(ev.w + ed4.w));
    }
    #pragma unroll
    for (int off = 32; off; off >>= 1) {
      m0 = fmaxf(m0, __shfl_xor(m0, off)); m1 = fmaxf(m1, __shfl_xor(m1, off));
      m2v = fmaxf(m2v, __shfl_xor(m2v, off)); m3 = fmaxf(m3, __shfl_xor(m3, off));
    }
    float t0 = 0.f, t1 = 0.f, t2 = 0.f, t3 = 0.f;
    for (int j = stF + lane; j < stF + lenF; j += 64) {
      int s = csr[j];
      float4 ev = ((const float4*)es)[s];
      t0 += __expf(leaky(ev.x + ed4.x) - m0); t1 += __expf(leaky(ev.y + ed4.y) - m1);
      t2 += __expf(leaky(ev.z + ed4.z) - m2v); t3 += __expf(leaky(ev.w + ed4.w) - m3);
    }
    #pragma unroll
    for (int off = 32; off; off >>= 1) {
      t0 += __shfl_xor(t0, off); t1 += __shfl_xor(t1, off);
      t2 += __shfl_xor(t2, off); t3 += __shfl_xor(t3, off);
    }
    float j0 = 1.f / (t0 + 1e-16f), j1 = 1.f / (t1 + 1e-16f);
    float j2 = 1.f / (t2 + 1e-16f), j3 = 1.f / (t3 + 1e-16f);
    float edh = (hh & 2) ? ((hh & 1) ? ed4.w : ed4.z) : ((hh & 1) ? ed4.y : ed4.x);
    float mh  = (hh & 2) ? ((hh & 1) ? m3 : m2v) : ((hh & 1) ? m1 : m0);
    float ih  = (hh & 2) ? ((hh & 1) ? j3 : j2) : ((hh & 1) ? j1 : j0);
    float ax = 0.f, ay = 0.f;
    for (int j = stF; j < stF + lenF; ++j) {
      int s = csr[j];
      float lv = leaky(es[(size_t)s * 4 + hh] + edh);
      float a = __expf(lv - mh) * ih;
      unsigned u = h32[(size_t)s * 64 + lane];
      ax = fmaf(b2f_lo(u), a, ax);
      ay = fmaf(b2f_hi(u), a, ay);
    }
    float o0 = elu(ax + bias1[f]), o1 = elu(ay + bias1[f + 1]);
    unsigned packed = (unsigned)f2b(o0) | ((unsigned)f2b(o1) << 16);
    ((unsigned*)hmidb)[(size_t)nI * 64 + lane] = packed;
  }
}

// ---------- GEMM 2 (MFMA): h2b(bf16) = hmidb(bf16) @ W2, + scores ----------
__global__ __launch_bounds__(256) void gemm2_kernel(
    const unsigned short* __restrict__ xb, const unsigned short* __restrict__ Wt2g,
    const float* __restrict__ asr, const float* __restrict__ ads,
    unsigned short* __restrict__ h2b, float* __restrict__ es, float* __restrict__ ed,
    int N) {
  __shared__ short Wt[64 * LDSTRIDE];
  __shared__ short As[64 * LDSTRIDE];
  int tid = threadIdx.x;
  int row0 = blockIdx.x * 64;
  int lane = tid & 63, wv = tid >> 6;
  int m2 = lane & 15, quad = lane >> 4;

  for (int i = tid; i < 64 * 16; i += 256) {
    int c = i >> 4, ch = i & 15;
    *(uint4*)&Wt[c * LDSTRIDE + ch * 8] = *(const uint4*)&Wt2g[c * 128 + ch * 8];
  }
  for (int idx = tid; idx < 64 * 16; idx += 256) {
    int r = idx >> 4, ch = idx & 15;
    int n = row0 + r;
    uint4 u = (n < N) ? *(const uint4*)&xb[(size_t)n * 128 + ch * 8]
                      : make_uint4(0, 0, 0, 0);
    *(uint4*)&As[r * LDSTRIDE + ch * 8] = u;
  }
  __syncthreads();

  facc4 acc[4] = {};
  const short* Abase = &As[(wv * 16 + m2) * LDSTRIDE];
  #pragma unroll
  for (int ks = 0; ks < 4; ++ks) {
    int k = ks * 32 + quad * 8;
    bfrag8 af = *(const bfrag8*)&Abase[k];
    #pragma unroll
    for (int t = 0; t < 4; ++t) {
      bfrag8 bf = *(const bfrag8*)&Wt[(t * 16 + m2) * LDSTRIDE + k];
      acc[t] = __builtin_amdgcn_mfma_f32_16x16x32_bf16(af, bf, acc[t], 0, 0, 0);
    }
  }

  float av[4], bv[4];
  #pragma unroll
  for (int t = 0; t < 4; ++t) {
    av[t] = asr[t * 16 + m2]; bv[t] = ads[t * 16 + m2];
  }
  #pragma unroll
  for (int r = 0; r < 4; ++r) {
    int n = row0 + wv * 16 + quad * 4 + r;
    bool valid = (n < N);
    if (valid) {
      #pragma unroll
      for (int t = 0; t < 4; ++t)
        h2b[(size_t)n * 64 + t * 16 + m2] = f2b(acc[t][r]);
    }
    float ps = acc[0][r] * av[0] + acc[1][r] * av[1] + acc[2][r] * av[2] + acc[3][r] * av[3];
    float pd = acc[0][r] * bv[0] + acc[1][r] * bv[1] + acc[2][r] * bv[2] + acc[3][r] * bv[3];
    ps += __shfl_xor(ps, 1); ps += __shfl_xor(ps, 2); ps += __shfl_xor(ps, 4); ps += __shfl_xor(ps, 8);
    pd += __shfl_xor(pd, 1); pd += __shfl_xor(pd, 2); pd += __shfl_xor(pd, 4); pd += __shfl_xor(pd, 8);
    if (valid && m2 == 0) { es[n] = ps; ed[n] = pd; }
  }
}

// ---------- Aggregation layer 2 (R9 version, untouched) ----------
__global__ __launch_bounds__(256) void agg2_kernel(
    const int* __restrict__ rowptr, const int* __restrict__ rowdeg, const int* __restrict__ csr,
    const float* __restrict__ es, const float* __restrict__ ed,
    const unsigned short* __restrict__ h2b, const float* __restrict__ bias2,
    float* __restrict__ out, int N) {
  __shared__ float lds_a[4][4][SEG + 8];
  __shared__ int   lds_s[4][4][SEG + 8];
  int tid = threadIdx.x;
  int wv = tid >> 6, lane = tid & 63;
  int sub = lane >> 4, sj = lane & 15;
  int nbase = blockIdx.x * 16 + wv * 4;
  int n = nbase + sub;
  bool nvalid = (n < N);
  int start = 0, len = 0;
  if (nvalid) { start = rowptr[n]; len = rowdeg[n]; }
  int lenc = (len <= SEG) ? len : 0;

  float edv = nvalid ? ed[n] : 0.f;
  float l[4];
  float mx = -1e30f;
  #pragma unroll
  for (int it = 0; it < 4; ++it) {
    int j = sj + it * 16;
    if (j < lenc) {
      int s = csr[start + j];
      lds_s[wv][sub][j] = s;
      float lv = leaky(es[s] + edv);
      l[it] = lv;
      mx = fmaxf(mx, lv);
    } else {
      l[it] = -1e30f;
    }
  }
  #pragma unroll
  for (int off = 1; off < 16; off <<= 1) mx = fmaxf(mx, __shfl_xor(mx, off));
  float sm = 0.f;
  #pragma unroll
  for (int it = 0; it < 4; ++it) {
    float p = __expf(l[it] - mx);
    l[it] = p;
    sm += p;
  }
  #pragma unroll
  for (int off = 1; off < 16; off <<= 1) sm += __shfl_xor(sm, off);
  float inv = __builtin_amdgcn_rcpf(sm + 1e-16f);
  #pragma unroll
  for (int it = 0; it < 4; ++it) {
    int j = sj + it * 16;
    if (j < lenc) lds_a[wv][sub][j] = l[it] * inv;
  }
  if (sj == 0) {
    int lenp1 = (lenc + 7) & ~7;
    for (int t = lenc; t < lenp1; ++t) {
      lds_s[wv][sub][t] = 0;
      lds_a[wv][sub][t] = 0.f;
    }
  }
  wave_lds_fence();

  int fl = lane & 7, eidx = lane >> 3;
  const uint4* hrow = (const uint4*)h2b;
  #pragma unroll 1
  for (int i = 0; i < 4; ++i) {
    int lenC = __shfl(lenc, i << 4);
    if (lenC == 0) continue;
    int nI = nbase + i;
    const float* aP = &lds_a[wv][i][0];
    const int*   sP = &lds_s[wv][i][0];
    int lenp = (lenC + 7) & ~7;
    v2f C0 = {0.f, 0.f}, C1 = {0.f, 0.f}, C2 = {0.f, 0.f}, C3 = {0.f, 0.f};
    v2f D0 = {0.f, 0.f}, D1 = {0.f, 0.f}, D2 = {0.f, 0.f}, D3 = {0.f, 0.f};
    int g = 0;
    for (; g + 16 <= lenp; g += 16) {
      int sA = sP[g + eidx],   sB = sP[g + 8 + eidx];
      float wA = aP[g + eidx], wB = aP[g + 8 + eidx];
      uint4 uA = hrow[(size_t)sA * 8 + fl];
      uint4 uB = hrow[(size_t)sB * 8 + fl];
      v2f wA2 = {wA, wA}, wB2 = {wB, wB};
      C0 = __builtin_elementwise_fma(b2f2(uA.x), wA2, C0);
      C1 = __builtin_elementwise_fma(b2f2(uA.y), wA2, C1);
      C2 = __builtin_elementwise_fma(b2f2(uA.z), wA2, C2);
      C3 = __builtin_elementwise_fma(b2f2(uA.w), wA2, C3);
      D0 = __builtin_elementwise_fma(b2f2(uB.x), wB2, D0);
      D1 = __builtin_elementwise_fma(b2f2(uB.y), wB2, D1);
      D2 = __builtin_elementwise_fma(b2f2(uB.z), wB2, D2);
      D3 = __builtin_elementwise_fma(b2f2(uB.w), wB2, D3);
    }
    if (g < lenp) {
      int sA = sP[g + eidx];
      float wA = aP[g + eidx];
      uint4 uA = hrow[(size_t)sA * 8 + fl];
      v2f wA2 = {wA, wA};
      C0 = __builtin_elementwise_fma(b2f2(uA.x), wA2, C0);
      C1 = __builtin_elementwise_fma(b2f2(uA.y), wA2, C1);
      C2 = __builtin_elementwise_fma(b2f2(uA.z), wA2, C2);
      C3 = __builtin_elementwise_fma(b2f2(uA.w), wA2, C3);
    }
    C0 += D0; C1 += D1; C2 += D2; C3 += D3;
    float c0 = C0.x, c1 = C0.y, c2 = C1.x, c3 = C1.y;
    float c4 = C2.x, c5 = C2.y, c6 = C3.x, c7 = C3.y;
    c0 += __shfl_xor(c0, 8);  c1 += __shfl_xor(c1, 8);  c2 += __shfl_xor(c2, 8);  c3 += __shfl_xor(c3, 8);
    c4 += __shfl_xor(c4, 8);  c5 += __shfl_xor(c5, 8);  c6 += __shfl_xor(c6, 8);  c7 += __shfl_xor(c7, 8);
    c0 += __shfl_xor(c0, 16); c1 += __shfl_xor(c1, 16); c2 += __shfl_xor(c2, 16); c3 += __shfl_xor(c3, 16);
    c4 += __shfl_xor(c4, 16); c5 += __shfl_xor(c5, 16); c6 += __shfl_xor(c6, 16); c7 += __shfl_xor(c7, 16);
    c0 += __shfl_xor(c0, 32); c1 += __shfl_xor(c1, 32); c2 += __shfl_xor(c2, 32); c3 += __shfl_xor(c3, 32);
    c4 += __shfl_xor(c4, 32); c5 += __shfl_xor(c5, 32); c6 += __shfl_xor(c6, 32); c7 += __shfl_xor(c7, 32);
    if (eidx == 0) {
      float4 ba = *(const float4*)&bias2[fl * 8];
      float4 bb = *(const float4*)&bias2[fl * 8 + 4];
      ((float4*)out)[(size_t)nI * 16 + fl * 2]     = make_float4(c0 + ba.x, c1 + ba.y, c2 + ba.z, c3 + ba.w);
      ((float4*)out)[(size_t)nI * 16 + fl * 2 + 1] = make_float4(c4 + bb.x, c5 + bb.y, c6 + bb.z, c7 + bb.w);
    }
  }

  // fallback for len > SEG
  #pragma unroll 1
  for (int i = 0; i < 4; ++i) {
    int lenF = __shfl(len, i << 4);
    if (lenF <= SEG) continue;
    int stF = __shfl(start, i << 4);
    int nI = nbase + i;
    float edF = ed[nI];
    float m = -1e30f;
    for (int j = stF + lane; j < stF + lenF; j += 64) {
      m = fmaxf(m, leaky(es[csr[j]] + edF));
    }
    #pragma unroll
    for (int off = 32; off; off >>= 1) m = fmaxf(m, __shfl_xor(m, off));
    float t = 0.f;
    for (int j = stF + lane; j < stF + lenF; j += 64) {
      t += __expf(leaky(es[csr[j]] + edF) - m);
    }
    #pragma unroll
    for (int off = 32; off; off >>= 1) t += __shfl_xor(t, off);
    float iv = 1.f / (t + 1e-16f);
    float acc = 0.f;
    for (int j = stF; j < stF + lenF; ++j) {
      int s = csr[j];
      float a = __expf(leaky(es[s] + edF) - m) * iv;
      float v = __uint_as_float(((unsigned)h2b[(size_t)s * 64 + lane]) << 16);
      acc = fmaf(v, a, acc);
    }
    out[(size_t)nI * 64 + lane] = acc + bias2[lane];
  }
}

extern "C" void kernel_launch(void* const* d_in, const int* in_sizes, int n_in,
                              void* d_out, int out_size, void* d_ws, size_t ws_size,
                              hipStream_t stream) {
  const float* x   = (const float*)d_in[0];
  const int*   ei  = (const int*)d_in[1];
  const float* W1  = (const float*)d_in[2];
  const float* as1 = (const float*)d_in[3];
  const float* ad1 = (const float*)d_in[4];
  const float* b1  = (const float*)d_in[5];
  const float* W2  = (const float*)d_in[6];
  const float* as2 = (const float*)d_in[7];
  const float* ad2 = (const float*)d_in[8];
  const float* b2  = (const float*)d_in[9];
  float* out = (float*)d_out;

  int N = in_sizes[0] / IN_F;
  int E = in_sizes[1] / 2;
  int Etot = E + N;
  int NB = (N + 127) >> BSHIFT;

  char* p = (char*)d_ws;
  auto carve = [&](size_t bytes) -> char* {
    char* r = p;
    p += (bytes + 255) & ~(size_t)255;
    return r;
  };
  int* flag     = (int*)carve(4);
  int* bcur     = (int*)carve((size_t)NBMAX * 4);
  unsigned short* Wt1g = (unsigned short*)carve(128 * 128 * 2);
  unsigned short* Wt2g = (unsigned short*)carve(64 * 128 * 2);
  unsigned* ebuf = (unsigned*)carve((size_t)NB * SLOT * 4);
  int* rowptr   = (int*)carve((size_t)(N + 1) * 4);
  int* rowdeg   = (int*)carve((size_t)(N + 1) * 4);
  int* csr      = (int*)carve((size_t)NB * SLOT * 4);
  float* es1    = (float*)carve((size_t)N * 4 * 4);
  float* ed1    = (float*)carve((size_t)N * 4 * 4);
  float* es2    = (float*)carve((size_t)N * 4);
  float* ed2    = (float*)carve((size_t)N * 4);
  unsigned short* h1b   = (unsigned short*)carve((size_t)N * 128 * 2);
  unsigned short* hmidb = (unsigned short*)carve((size_t)N * 128 * 2);
  unsigned short* h2b   = (unsigned short*)carve((size_t)N * 64 * 2);

  int nchunk = (Etot + CHUNK - 1) / CHUNK;
  int gblocks = (N + 63) / 64;
  prologue_kernel<<<14, 256, 0, stream>>>(ei, E, flag, bcur, NB, W1, W2, Wt1g, Wt2g);
  bscatter_kernel<<<nchunk, 256, 0, stream>>>(ei, E, Etot, flag, NB, bcur, ebuf);
  bcsr_gemm1_kernel<<<NB + gblocks, 256, 0, stream>>>(
      bcur, ebuf, rowptr, rowdeg, csr, NB,
      x, Wt1g, as1, ad1, h1b, es1, ed1, N);
  agg1_kernel<<<(N + 15) / 16, 256, 0, stream>>>(rowptr, rowdeg, csr, es1, ed1, h1b, b1, hmidb, N);
  gemm2_kernel<<<(N + 63) / 64, 256, 0, stream>>>(hmidb, Wt2g, as2, ad2, h2b, es2, ed2, N);
  agg2_kernel<<<(N + 15) / 16, 256, 0, stream>>>(rowptr, rowdeg, csr, es2, ed2, h2b, b2, out, N);
}